// Round 3
// baseline (686.338 us; speedup 1.0000x reference)
//
#include <hip/hip_runtime.h>

// ScalarVectorAttentionReadout — MI355X (gfx950)
//
// Pipeline (all on `stream`, graph-capture safe):
//  P0  hipMemsetAsync : zero Mg (ordered-uint max), denom, graph_emb
//  P1  k_pack         : gW1 fp32 -> f16, MFMA-B fragment order (L2-resident, 114KB)
//  K1  k_gate         : hidden = x@W1 (f16 MFMA, fp32 accum), fuse +b1, leaky,
//                       @W2 + b2 in-register (shuffle reduce) -> gate[N] fp32
//  K2a k_segmax       : per-graph max of gate (LDS slot pre-reduce, ordered-uint atomics)
//  K2b k_expsum       : a_un = exp(gate - Mg[g]), denom[g] += a_un
//  K3  k_wsum         : graph_emb[g] += (a_un/denom) * x   (1 col/thread, segment regs)
//  K4  k_final        : out = lrelu(emb@mW1+mb1)@mW2+mb2   (fp32)
//
// Precision: f16 (not bf16) for the big GEMM -> ~1e-3 output absmax vs 5.78e-3 threshold.

#define NNODES 262144
#define NGRAPH 1024
#define SD 256   // scalar feature dim
#define VD 192   // 64*3 vector dims flattened
#define IND 448
#define HID 128

typedef _Float16 f16x8 __attribute__((ext_vector_type(8)));
typedef float f32x4 __attribute__((ext_vector_type(4)));

__device__ __forceinline__ unsigned ordkey(float f) {
  unsigned u = __float_as_uint(f);
  return (u & 0x80000000u) ? ~u : (u | 0x80000000u);
}
__device__ __forceinline__ float ordinv(unsigned k) {
  return __uint_as_float((k & 0x80000000u) ? (k ^ 0x80000000u) : ~k);
}
__device__ __forceinline__ float lrelu(float v) { return v >= 0.f ? v : 0.01f * v; }

// ---------------- P1: pack gW1 into f16 MFMA B-fragment order ----------------
// Bp flat index o = ((s*8 + f)*64 + lane)*8 + j  maps to  gW1[k*128 + n]
// with k = s*32 + (lane>>4)*8 + j,  n = f*16 + (lane&15).
__global__ void k_pack(const float* __restrict__ gW1, _Float16* __restrict__ Bp) {
  int o = blockIdx.x * 256 + threadIdx.x;
  if (o >= IND * HID) return;
  int j = o & 7, l = (o >> 3) & 63, f = (o >> 9) & 7, s = o >> 12;
  int k = s * 32 + (l >> 4) * 8 + j;
  int n = f * 16 + (l & 15);
  Bp[o] = (_Float16)gW1[k * HID + n];
}

__device__ __forceinline__ f16x8 load_cvt8(const float* __restrict__ p) {
  f32x4 lo = *(const f32x4*)p;
  f32x4 hi = *(const f32x4*)(p + 4);
  f16x8 r;
  r[0] = (_Float16)lo[0]; r[1] = (_Float16)lo[1];
  r[2] = (_Float16)lo[2]; r[3] = (_Float16)lo[3];
  r[4] = (_Float16)hi[0]; r[5] = (_Float16)hi[1];
  r[6] = (_Float16)hi[2]; r[7] = (_Float16)hi[3];
  return r;
}

// ---------------- K1: gate GEMM (block = 4 waves, 128 rows x 128 cols) -------
// No LDS, no barriers. Per wave: 32 rows x 128 cols = 2x8 frags of 16x16,
// A frags direct from global (rows are 128B-aligned chunks), B frags from Bp.
__global__ __launch_bounds__(256) void k_gate(
    const float* __restrict__ xs, const float* __restrict__ xv,
    const _Float16* __restrict__ Bp, const float* __restrict__ gb1,
    const float* __restrict__ gW2, const float* __restrict__ gb2,
    float* __restrict__ gate) {
  const int wid = threadIdx.x >> 6;
  const int lane = threadIdx.x & 63;
  const int l15 = lane & 15, l4 = lane >> 4;
  const int row0 = blockIdx.x * 128 + wid * 32;

  f32x4 acc[2][8];
#pragma unroll
  for (int rf = 0; rf < 2; ++rf)
#pragma unroll
    for (int cf = 0; cf < 8; ++cf) acc[rf][cf] = {0.f, 0.f, 0.f, 0.f};

  const f16x8* bp = (const f16x8*)Bp + lane;
  const float* s0 = xs + (size_t)(row0 + l15) * SD + l4 * 8;
  const float* s1 = xs + (size_t)(row0 + 16 + l15) * SD + l4 * 8;
  const float* v0 = xv + (size_t)(row0 + l15) * VD + l4 * 8;
  const float* v1 = xv + (size_t)(row0 + 16 + l15) * VD + l4 * 8;

  for (int s = 0; s < 14; ++s) {
    f16x8 a0, a1;
    if (s < 8) {
      a0 = load_cvt8(s0 + s * 32);
      a1 = load_cvt8(s1 + s * 32);
    } else {
      a0 = load_cvt8(v0 + (s - 8) * 32);
      a1 = load_cvt8(v1 + (s - 8) * 32);
    }
    f16x8 b[8];
#pragma unroll
    for (int f = 0; f < 8; ++f) b[f] = bp[(s * 8 + f) * 64];
#pragma unroll
    for (int cf = 0; cf < 8; ++cf) {
      acc[0][cf] = __builtin_amdgcn_mfma_f32_16x16x32_f16(a0, b[cf], acc[0][cf], 0, 0, 0);
      acc[1][cf] = __builtin_amdgcn_mfma_f32_16x16x32_f16(a1, b[cf], acc[1][cf], 0, 0, 0);
    }
  }

  // Epilogue: gate = lrelu(hid + b1) @ W2 + b2, reduced across cols.
  // C/D layout (m89): col = cf*16 + (lane&15), row = rf*16 + (lane>>4)*4 + reg.
  float b1v[8], w2v[8];
#pragma unroll
  for (int cf = 0; cf < 8; ++cf) {
    b1v[cf] = gb1[cf * 16 + l15];
    w2v[cf] = gW2[cf * 16 + l15];
  }
  float gb2v = gb2[0];
#pragma unroll
  for (int rf = 0; rf < 2; ++rf) {
    float p[4] = {0.f, 0.f, 0.f, 0.f};
#pragma unroll
    for (int cf = 0; cf < 8; ++cf) {
#pragma unroll
      for (int r = 0; r < 4; ++r) {
        float v = lrelu(acc[rf][cf][r] + b1v[cf]);
        p[r] = fmaf(v, w2v[cf], p[r]);
      }
    }
#pragma unroll
    for (int d = 1; d < 16; d <<= 1) {
#pragma unroll
      for (int r = 0; r < 4; ++r) p[r] += __shfl_xor(p[r], d);
    }
    if (l15 == 0) {
#pragma unroll
      for (int r = 0; r < 4; ++r)
        gate[row0 + rf * 16 + l4 * 4 + r] = p[r] + gb2v;
    }
  }
}

// ---------------- K2a: per-graph max of gate -------------------------------
__global__ __launch_bounds__(256) void k_segmax(const float* __restrict__ gate,
                                                const int* __restrict__ batch,
                                                unsigned* __restrict__ Mg) {
  __shared__ unsigned slots[NGRAPH];
  int t = threadIdx.x;
  int r0 = blockIdx.x * 256;
  for (int i = t; i < NGRAPH; i += 256) slots[i] = 0u;
  __syncthreads();
  int gfirst = batch[r0];
  int g = batch[r0 + t];
  atomicMax(&slots[g - gfirst], ordkey(gate[r0 + t]));
  __syncthreads();
  int span = batch[r0 + 255] - gfirst;
  for (int i = t; i <= span; i += 256)
    if (slots[i]) atomicMax(&Mg[gfirst + i], slots[i]);
}

// ---------------- K2b: a_un = exp(gate - max), denom += a_un ----------------
__global__ __launch_bounds__(256) void k_expsum(const float* __restrict__ gate,
                                                const int* __restrict__ batch,
                                                const unsigned* __restrict__ Mg,
                                                float* __restrict__ aun,
                                                float* __restrict__ den) {
  __shared__ float slots[NGRAPH];
  int t = threadIdx.x;
  int r0 = blockIdx.x * 256;
  for (int i = t; i < NGRAPH; i += 256) slots[i] = 0.f;
  __syncthreads();
  int gfirst = batch[r0];
  int g = batch[r0 + t];
  float m = ordinv(Mg[g]);
  float au = expf(gate[r0 + t] - m);
  aun[r0 + t] = au;
  atomicAdd(&slots[g - gfirst], au);
  __syncthreads();
  int span = batch[r0 + 255] - gfirst;
  for (int i = t; i <= span; i += 256)
    if (slots[i] != 0.f) atomicAdd(&den[gfirst + i], slots[i]);
}

// ---------------- K3: weighted segment sum ----------------------------------
// 448 threads = one column each; 256 rows per block; register accumulation per
// sorted segment, atomic flush at segment/chunk boundaries.
__global__ __launch_bounds__(448) void k_wsum(
    const float* __restrict__ xs, const float* __restrict__ xv,
    const int* __restrict__ batch, const float* __restrict__ aun,
    const float* __restrict__ den, float* __restrict__ emb) {
  __shared__ float wl[256];
  __shared__ int bl[257];
  int t = threadIdx.x;
  int r0 = blockIdx.x * 256;
  if (t < 256) {
    int g = batch[r0 + t];
    bl[t] = g;
    wl[t] = aun[r0 + t] / (den[g] + 1e-16f);
  }
  if (t == 0) bl[256] = -1;  // force flush at chunk end
  __syncthreads();

  const float* src;
  size_t stride;
  if (t < SD) { src = xs + (size_t)r0 * SD + t; stride = SD; }
  else        { src = xv + (size_t)r0 * VD + (t - SD); stride = VD; }

  float acc = 0.f;
#pragma unroll 4
  for (int i = 0; i < 256; ++i) {
    acc = fmaf(wl[i], src[(size_t)i * stride], acc);
    if (bl[i + 1] != bl[i]) {
      atomicAdd(&emb[(size_t)bl[i] * IND + t], acc);
      acc = 0.f;
    }
  }
}

// ---------------- K4: final MLP (fp32) --------------------------------------
__global__ __launch_bounds__(128) void k_final(
    const float* __restrict__ emb, const float* __restrict__ W1,
    const float* __restrict__ b1, const float* __restrict__ W2,
    const float* __restrict__ b2, float* __restrict__ out) {
  __shared__ float embL[4 * IND];
  __shared__ float hidL[4 * HID];
  int t = threadIdx.x;
  int g0 = blockIdx.x * 4;
  for (int i = t; i < 4 * IND; i += 128) embL[i] = emb[(size_t)g0 * IND + i];
  __syncthreads();
  float a0 = b1[t], a1 = a0, a2 = a0, a3 = a0;
  for (int k = 0; k < IND; ++k) {
    float w = W1[k * HID + t];
    a0 = fmaf(embL[k], w, a0);
    a1 = fmaf(embL[IND + k], w, a1);
    a2 = fmaf(embL[2 * IND + k], w, a2);
    a3 = fmaf(embL[3 * IND + k], w, a3);
  }
  hidL[t] = lrelu(a0);
  hidL[HID + t] = lrelu(a1);
  hidL[2 * HID + t] = lrelu(a2);
  hidL[3 * HID + t] = lrelu(a3);
  __syncthreads();
  float o0 = b2[t], o1 = o0, o2 = o0, o3 = o0;
  for (int h = 0; h < HID; ++h) {
    float w = W2[h * HID + t];
    o0 = fmaf(hidL[h], w, o0);
    o1 = fmaf(hidL[HID + h], w, o1);
    o2 = fmaf(hidL[2 * HID + h], w, o2);
    o3 = fmaf(hidL[3 * HID + h], w, o3);
  }
  out[(size_t)g0 * HID + t] = o0;
  out[(size_t)(g0 + 1) * HID + t] = o1;
  out[(size_t)(g0 + 2) * HID + t] = o2;
  out[(size_t)(g0 + 3) * HID + t] = o3;
}

extern "C" void kernel_launch(void* const* d_in, const int* in_sizes, int n_in,
                              void* d_out, int out_size, void* d_ws, size_t ws_size,
                              hipStream_t stream) {
  const float* xs  = (const float*)d_in[0];   // scalar  (N,256)
  const float* xv  = (const float*)d_in[1];   // vector  (N,192)
  const int* batch = (const int*)d_in[2];     // (N,) sorted graph ids
  const float* gW1 = (const float*)d_in[3];
  const float* gb1 = (const float*)d_in[4];
  const float* gW2 = (const float*)d_in[5];
  const float* gb2 = (const float*)d_in[6];
  const float* mW1 = (const float*)d_in[7];
  const float* mb1 = (const float*)d_in[8];
  const float* mW2 = (const float*)d_in[9];
  const float* mb2 = (const float*)d_in[10];
  float* out = (float*)d_out;

  char* ws = (char*)d_ws;
  const size_t OFF_BP   = 0;                               // 114688 B (f16 W pack)
  const size_t OFF_GATE = 128 * 1024;                      // N*4 = 1 MB
  const size_t OFF_AUN  = OFF_GATE + (size_t)NNODES * 4;   // N*4 = 1 MB
  const size_t OFF_MG   = OFF_AUN + (size_t)NNODES * 4;    // G*4
  const size_t OFF_DEN  = OFF_MG + (size_t)NGRAPH * 4;     // G*4
  const size_t OFF_EMB  = OFF_DEN + (size_t)NGRAPH * 4;    // G*448*4
  (void)OFF_BP; (void)ws_size; (void)n_in; (void)in_sizes; (void)out_size;

  _Float16* Bp = (_Float16*)(ws);
  float* gate  = (float*)(ws + OFF_GATE);
  float* aun   = (float*)(ws + OFF_AUN);
  unsigned* Mg = (unsigned*)(ws + OFF_MG);
  float* den   = (float*)(ws + OFF_DEN);
  float* emb   = (float*)(ws + OFF_EMB);

  // zero Mg + den + emb in one contiguous memset
  size_t zbytes = (size_t)NGRAPH * 4 + (size_t)NGRAPH * 4 + (size_t)NGRAPH * IND * 4;
  hipMemsetAsync(ws + OFF_MG, 0, zbytes, stream);

  k_pack<<<(IND * HID + 255) / 256, 256, 0, stream>>>(gW1, Bp);
  k_gate<<<NNODES / 128, 256, 0, stream>>>(xs, xv, Bp, gb1, gW2, gb2, gate);
  k_segmax<<<NNODES / 256, 256, 0, stream>>>(gate, batch, Mg);
  k_expsum<<<NNODES / 256, 256, 0, stream>>>(gate, batch, Mg, aun, den);
  k_wsum<<<NNODES / 256, 448, 0, stream>>>(xs, xv, batch, aun, den, emb);
  k_final<<<NGRAPH / 4, 128, 0, stream>>>(emb, mW1, mb1, mW2, mb2, out);
}